// Round 12
// baseline (237.959 us; speedup 1.0000x reference)
//
#include <hip/hip_runtime.h>

typedef unsigned short ushort_t;
typedef __attribute__((ext_vector_type(8))) __bf16 bf16x8;
typedef __attribute__((ext_vector_type(8))) unsigned short us8;
typedef __attribute__((ext_vector_type(4))) float f32x4;

// async global->LDS, 16B per lane. LDS dest is wave-uniform base + lane*16 (m97/m104).
#define GLOAD_LDS16(gp, lp)                                                              \
  __builtin_amdgcn_global_load_lds(                                                     \
      (const __attribute__((address_space(1))) unsigned int*)(gp),                      \
      (__attribute__((address_space(3))) unsigned int*)(lp), 16, 0, 0)

#define MEMFENCE() asm volatile("" ::: "memory")
#define SBARRIER()                          \
  do {                                      \
    MEMFENCE();                             \
    __builtin_amdgcn_s_barrier();           \
    MEMFENCE();                             \
  } while (0)
#define WAIT_VM2() asm volatile("s_waitcnt vmcnt(2)" ::: "memory")
#define WAIT_VM0() asm volatile("s_waitcnt vmcnt(0)" ::: "memory")
#define WAIT_LGKM0P() asm volatile("s_waitcnt lgkmcnt(0)" ::: "memory")
#define WAIT_LGKM8() asm volatile("s_waitcnt lgkmcnt(8)" ::: "memory")

__device__ __forceinline__ ushort_t f2bf(float f) {
  unsigned u = __builtin_bit_cast(unsigned, f);
  u += 0x7fffu + ((u >> 16) & 1u);  // RNE
  return (ushort_t)(u >> 16);
}
__device__ __forceinline__ float bf2f(ushort_t h) {
  return __builtin_bit_cast(float, (unsigned)h << 16);
}

// ---------------- merged pack: x (8 elems/thr, 16B stores) + w4 + bias, one launch ----
__global__ __launch_bounds__(256) void k_pack_all(
    const float* __restrict__ x, const float* __restrict__ q_w,
    const float* __restrict__ k_w, const float* __restrict__ v_w,
    const float* __restrict__ o_w, const float* __restrict__ q_b,
    const float* __restrict__ k_b, const float* __restrict__ v_b,
    ushort_t* __restrict__ xb, ushort_t* __restrict__ wdst, float* __restrict__ biasq) {
  const int blk = blockIdx.x;
  if (blk < 8192) {  // x: 16,777,216 elems = 8192 blocks x 256 thr x 8
    long i = ((long)blk * 256 + threadIdx.x) * 8;
    float4 a = *reinterpret_cast<const float4*>(x + i);
    float4 b = *reinterpret_cast<const float4*>(x + i + 4);
    us8 o;
    o[0] = f2bf(a.x); o[1] = f2bf(a.y); o[2] = f2bf(a.z); o[3] = f2bf(a.w);
    o[4] = f2bf(b.x); o[5] = f2bf(b.y); o[6] = f2bf(b.z); o[7] = f2bf(b.w);
    *reinterpret_cast<us8*>(xb + i) = o;
  } else if (blk < 12288) {  // weights: 4096 blocks
    const int wb = blk - 8192;
    const int wsel = wb >> 10;
    const float* src = wsel == 0 ? q_w : wsel == 1 ? k_w : wsel == 2 ? v_w : o_w;
    const int off = (wb & 1023) * 1024 + threadIdx.x * 4;
    float4 v = *reinterpret_cast<const float4*>(src + off);
    ushort4 o;
    o.x = f2bf(v.x); o.y = f2bf(v.y); o.z = f2bf(v.z); o.w = f2bf(v.w);
    *reinterpret_cast<ushort4*>(wdst + wsel * 1048576 + off) = o;
  } else {  // bias: 12 blocks -> 3072
    int i = (blk - 12288) * 256 + threadIdx.x;
    const float* s = i < 1024 ? q_b : (i < 2048 ? k_b : v_b);
    biasq[i] = s[i & 1023];
  }
}

// ---------------- 128x128 4-phase GEMM, BK=64, 8 waves (2Mx4N), 2 blocks/CU ----------
// R12 occupancy experiment: half-scale mirror of the converged R6/R9 schedule.
// LDS: buf(2) x op(A,B) slots of [128][64] bf16 (16 KiB each) = 64 KiB -> 2 blocks/CU
// (16 waves/CU, 4/SIMD) so a co-resident block's MFMA covers this block's barrier drains.
// T2 swizzle (G4): read byte = row*128 + (kbyte ^ ((row&7)<<4)); LDS dest linear,
// inverse swizzle on GLOBAL source k-unit (rule #21). stage_half/read_frag verbatim R9.
// Iteration = 2 K-tiles (T->buf0, T+1->buf1), 2 phases each; vmcnt(2) at P2/P4 leaves
// only the next-next tile's A outstanding (T+1 / T+2 fully landed before their reads).

__device__ __forceinline__ void stage_half(const ushort_t* __restrict__ g, int ld, int kt,
                                           ushort_t* slot, int w, int lane) {
  const int swz = ((lane & 7) ^ (lane >> 3)) * 8;  // inverse st swizzle on source (elems)
#pragma unroll
  for (int l = 0; l < 2; l++) {
    int row = l * 64 + w * 8 + (lane >> 3);
    GLOAD_LDS16(g + (long)row * ld + kt + swz, slot + l * 4096 + w * 512);
  }
}

__device__ __forceinline__ bf16x8 read_frag(const ushort_t* slot, int row, int kbyte) {
  int byte = row * 128 + (kbyte ^ ((row & 7) << 4));  // 3-bit XOR: 8-slot spread
  return *reinterpret_cast<const bf16x8*>(reinterpret_cast<const char*>(slot) + byte);
}

template <bool OUT_F32>
__global__ __launch_bounds__(512, 4) void k_gemm128(
    const ushort_t* __restrict__ A, int lda, long strideA,
    const ushort_t* __restrict__ Bw, int ldb, long strideB,
    const float* __restrict__ bias, int relu_lim,
    void* __restrict__ Cout, int ldc, long strideC, int K) {
  __shared__ ushort_t lds[32768];  // 64 KiB
  const int t = threadIdx.x;
  const int lane = t & 63;
  const int w = t >> 6;
  const int wm = w >> 2, wn = w & 3;  // wave tile 64x32 at (wm*64, wn*32)
  const int z = blockIdx.z;

  // XCD-aware swizzle (nwg % 8 == 0 in all our launches -> simple form bijective)
  const int nx = gridDim.x;
  const int nwg = nx * gridDim.y;
  const int lin = blockIdx.x + blockIdx.y * nx;
  const int q8 = nwg >> 3;
  const int s = (lin & 7) * q8 + (lin >> 3);
  const long rowBase = (long)(s / nx) * 128;
  const long colBase = (long)(s % nx) * 128;

  const ushort_t* Ap = A + z * strideA + rowBase * lda;
  const ushort_t* Bp = Bw + z * strideB + colBase * ldb;

#define SLOT(buf, isB) (lds + (buf) * 16384 + (isB) * 8192)
#define STAGE(gb, ld, kt, buf, isB) stage_half((gb), (ld), (kt), SLOT(buf, isB), w, lane)

  f32x4 acc[4][2];
#pragma unroll
  for (int mi = 0; mi < 4; mi++)
#pragma unroll
    for (int ni = 0; ni < 2; ni++) acc[mi][ni] = (f32x4){0.f, 0.f, 0.f, 0.f};
  bf16x8 Ar[4][2], Br[2][2];
  const int fr = lane & 15;
  const int kb = (lane >> 4) * 16;  // byte offset within 64-elem k (per ks add ks*64)

#define LOADA(buf)                                                                  \
  do {                                                                              \
    const ushort_t* sl = SLOT(buf, 0);                                              \
    _Pragma("unroll") for (int mi = 0; mi < 4; mi++)                                \
        _Pragma("unroll") for (int ks = 0; ks < 2; ks++)                            \
            Ar[mi][ks] = read_frag(sl, wm * 64 + mi * 16 + fr, ks * 64 + kb);       \
  } while (0)
#define LOADB(buf)                                                                  \
  do {                                                                              \
    const ushort_t* sl = SLOT(buf, 1);                                              \
    _Pragma("unroll") for (int nj = 0; nj < 2; nj++)                                \
        _Pragma("unroll") for (int ks = 0; ks < 2; ks++)                            \
            Br[nj][ks] = read_frag(sl, wn * 32 + nj * 16 + fr, ks * 64 + kb);       \
  } while (0)
#define MFMA8(ks)                                                                   \
  do {                                                                              \
    _Pragma("unroll") for (int mi = 0; mi < 4; mi++)                                \
        _Pragma("unroll") for (int nj = 0; nj < 2; nj++)                            \
            acc[mi][nj] = __builtin_amdgcn_mfma_f32_16x16x32_bf16(                  \
                Ar[mi][ks], Br[nj][ks], acc[mi][nj], 0, 0, 0);                      \
  } while (0)

  // Prologue: tile0 (A,B -> buf0) + tile1.A -> buf1; drain tile0 (vmcnt2 leaves T1.A).
  STAGE(Ap, lda, 0, 0, 0);
  STAGE(Bp, ldb, 0, 0, 1);
  STAGE(Ap, lda, 64, 1, 0);
  WAIT_VM2();
  SBARRIER();

  const int NT2 = K >> 7;  // 2 K-tiles per iteration: T=2it (buf0), T+1 (buf1)
  for (int it = 0; it < NT2; it++) {
    const int kt = it << 7;
    const int ktb = kt + 64;
    const int ktn = (kt + 128 < K) ? kt + 128 : K - 64;   // clamped dup-write: benign
    const int ktn2 = (kt + 192 < K) ? kt + 192 : K - 64;

    // P1: reads buf0 A+B (12 ds_read); stage T+1.B -> buf1
    LOADA(0); LOADB(0);
    STAGE(Bp, ldb, ktb, 1, 1);
    WAIT_LGKM8();
    SBARRIER();
    WAIT_LGKM0P();
    __builtin_amdgcn_s_setprio(1); MFMA8(0); __builtin_amdgcn_s_setprio(0);
    // P2: stage T+2.A -> buf0; drain all but newest (T+1 complete)
    STAGE(Ap, lda, ktn, 0, 0);
    SBARRIER();
    __builtin_amdgcn_s_setprio(1); MFMA8(1); __builtin_amdgcn_s_setprio(0);
    WAIT_VM2();
    SBARRIER();
    // P3: reads buf1 A+B; stage T+2.B -> buf0
    LOADA(1); LOADB(1);
    STAGE(Bp, ldb, ktn, 0, 1);
    WAIT_LGKM8();
    SBARRIER();
    WAIT_LGKM0P();
    __builtin_amdgcn_s_setprio(1); MFMA8(0); __builtin_amdgcn_s_setprio(0);
    // P4: stage T+3.A -> buf1; drain all but newest (T+2 complete)
    STAGE(Ap, lda, ktn2, 1, 0);
    SBARRIER();
    __builtin_amdgcn_s_setprio(1); MFMA8(1); __builtin_amdgcn_s_setprio(0);
    WAIT_VM2();
    SBARRIER();
  }

  // ---- Epilogue: drain in-flight stages, then per-wave LDS transpose -> 16B stores.
  WAIT_VM0();
  SBARRIER();
  {
    float* sl = reinterpret_cast<float*>(lds) + w * 1024;  // 4 KiB/wave: [16][36] f32 pad
    const int rowQ = (lane >> 4) * 4;
    float bv[2];
#pragma unroll
    for (int ni = 0; ni < 2; ni++) bv[ni] = bias[(int)colBase + wn * 32 + ni * 16 + fr];
    const int rr = lane >> 2;        // 0..15: readback row
    const int cq = (lane & 3) * 8;   // 0..24: readback col octet
#pragma unroll
    for (int mi = 0; mi < 4; mi++) {
#pragma unroll
      for (int ni = 0; ni < 2; ni++) {
        const bool doRelu = ((int)colBase + wn * 32 + ni * 16 + fr) < relu_lim;
#pragma unroll
        for (int r = 0; r < 4; r++) {
          float v = acc[mi][ni][r] + bv[ni];
          if (doRelu) v = fmaxf(v, 0.f);
          sl[(rowQ + r) * 36 + ni * 16 + fr] = v;
        }
      }
      asm volatile("s_waitcnt lgkmcnt(0)" ::: "memory");
      __builtin_amdgcn_sched_barrier(0);
      float4 v0 = *reinterpret_cast<const float4*>(&sl[rr * 36 + cq]);
      float4 v1 = *reinterpret_cast<const float4*>(&sl[rr * 36 + cq + 4]);
      const long row = rowBase + wm * 64 + mi * 16 + rr;
      const long gc = colBase + wn * 32 + cq;
      if (OUT_F32) {
        float* dst = (float*)Cout + z * strideC + row * (long)ldc + gc;
        *reinterpret_cast<float4*>(dst) = v0;
        *reinterpret_cast<float4*>(dst + 4) = v1;
      } else {
        ushort_t* dst = (ushort_t*)Cout + z * strideC + row * (long)ldc + gc;
        us8 o0;
        o0[0] = f2bf(v0.x); o0[1] = f2bf(v0.y); o0[2] = f2bf(v0.z); o0[3] = f2bf(v0.w);
        o0[4] = f2bf(v1.x); o0[5] = f2bf(v1.y); o0[6] = f2bf(v1.z); o0[7] = f2bf(v1.w);
        *reinterpret_cast<us8*>(dst) = o0;
      }
      asm volatile("s_waitcnt lgkmcnt(0)" ::: "memory");  // reads retired before next mi overwrite
    }
  }
#undef SLOT
#undef STAGE
#undef LOADA
#undef LOADB
#undef MFMA8
}

// ---------------- KV state partials: [8][64][64][64], 4-wave blocks, LDS block-reduce --
__global__ __launch_bounds__(256) void k_kv_partial(const ushort_t* __restrict__ qkv,
                                                    float* __restrict__ partial) {
  const int bh = blockIdx.x;     // 0..63
  const int chunk = blockIdx.y;  // 0..7
  const int b = bh >> 4, h = bh & 15;
  const int t = threadIdx.x;
  const int w = t >> 6, lane = t & 63;
  const int d0 = (lane >> 2) * 4;
  const int e0 = (lane & 3) * 16;
  __shared__ float smem[16384];  // 64 KiB: per-wave staging (32K), then reduce (64K)
  float* kk = smem + w * 2048;         // [16][64]
  float* vv = smem + w * 2048 + 1024;  // [16][64]
  float acc[4][16];
#pragma unroll
  for (int di = 0; di < 4; di++)
#pragma unroll
    for (int j = 0; j < 16; j++) acc[di][j] = 0.f;

  const long rowbase = (long)b * 4096 + (long)chunk * 512 + (long)w * 128;
  for (int itr = 0; itr < 8; itr++) {
    __syncthreads();
#pragma unroll
    for (int rep = 0; rep < 4; rep++) {
      int lin = rep * 64 + lane;        // 0..255
      int op = lin >> 7;                // reps 0,1 -> k; reps 2,3 -> v
      int r = (lin >> 3) & 15;
      int c8 = (lin & 7) * 8;
      long m = rowbase + itr * 16 + r;
      us8 u = *reinterpret_cast<const us8*>(&qkv[m * 3072 + (op ? 2048 : 1024) + h * 64 + c8]);
      float* dst = (op ? vv : kk) + r * 64 + c8;
      float4 lo = {bf2f(u[0]), bf2f(u[1]), bf2f(u[2]), bf2f(u[3])};
      float4 hi = {bf2f(u[4]), bf2f(u[5]), bf2f(u[6]), bf2f(u[7])};
      *reinterpret_cast<float4*>(dst) = lo;
      *reinterpret_cast<float4*>(dst + 4) = hi;
    }
    __syncthreads();
#pragma unroll
    for (int ss = 0; ss < 16; ss++) {
      const float4 kq = *reinterpret_cast<const float4*>(&kk[ss * 64 + d0]);
#pragma unroll
      for (int jj = 0; jj < 4; jj++) {
        const float4 vq = *reinterpret_cast<const float4*>(&vv[ss * 64 + e0 + jj * 4]);
        acc[0][jj * 4 + 0] = fmaf(kq.x, vq.x, acc[0][jj * 4 + 0]);
        acc[0][jj * 4 + 1] = fmaf(kq.x, vq.y, acc[0][jj * 4 + 1]);
        acc[0][jj * 4 + 2] = fmaf(kq.x, vq.z, acc[0][jj * 4 + 2]);
        acc[0][jj * 4 + 3] = fmaf(kq.x, vq.w, acc[0][jj * 4 + 3]);
        acc[1][jj * 4 + 0] = fmaf(kq.y, vq.x, acc[1][jj * 4 + 0]);
        acc[1][jj * 4 + 1] = fmaf(kq.y, vq.y, acc[1][jj * 4 + 1]);
        acc[1][jj * 4 + 2] = fmaf(kq.y, vq.z, acc[1][jj * 4 + 2]);
        acc[1][jj * 4 + 3] = fmaf(kq.y, vq.w, acc[1][jj * 4 + 3]);
        acc[2][jj * 4 + 0] = fmaf(kq.z, vq.x, acc[2][jj * 4 + 0]);
        acc[2][jj * 4 + 1] = fmaf(kq.z, vq.y, acc[2][jj * 4 + 1]);
        acc[2][jj * 4 + 2] = fmaf(kq.z, vq.z, acc[2][jj * 4 + 2]);
        acc[2][jj * 4 + 3] = fmaf(kq.z, vq.w, acc[2][jj * 4 + 3]);
        acc[3][jj * 4 + 0] = fmaf(kq.w, vq.x, acc[3][jj * 4 + 0]);
        acc[3][jj * 4 + 1] = fmaf(kq.w, vq.y, acc[3][jj * 4 + 1]);
        acc[3][jj * 4 + 2] = fmaf(kq.w, vq.z, acc[3][jj * 4 + 2]);
        acc[3][jj * 4 + 3] = fmaf(kq.w, vq.w, acc[3][jj * 4 + 3]);
      }
    }
  }
  // block reduce: waves write acc to LDS, then each thread sums 16 outputs across waves
  __syncthreads();
#pragma unroll
  for (int di = 0; di < 4; di++)
#pragma unroll
    for (int j4 = 0; j4 < 4; j4++)
      *reinterpret_cast<float4*>(&smem[(w * 64 + lane) * 64 + di * 16 + j4 * 4]) =
          make_float4(acc[di][j4 * 4], acc[di][j4 * 4 + 1], acc[di][j4 * 4 + 2],
                      acc[di][j4 * 4 + 3]);
  __syncthreads();
  const int u = (t >> 4) * 4 + (t & 3);  // owner lane of (d,e) block
  const int di = (t >> 2) & 3;
  float4 r0 = {0, 0, 0, 0}, r1 = {0, 0, 0, 0}, r2 = {0, 0, 0, 0}, r3 = {0, 0, 0, 0};
#pragma unroll
  for (int ww = 0; ww < 4; ww++) {
    const float* base = &smem[(ww * 64 + u) * 64 + di * 16];
    float4 a0 = *reinterpret_cast<const float4*>(base);
    float4 a1 = *reinterpret_cast<const float4*>(base + 4);
    float4 a2 = *reinterpret_cast<const float4*>(base + 8);
    float4 a3 = *reinterpret_cast<const float4*>(base + 12);
    r0.x += a0.x; r0.y += a0.y; r0.z += a0.z; r0.w += a0.w;
    r1.x += a1.x; r1.y += a1.y; r1.z += a1.z; r1.w += a1.w;
    r2.x += a2.x; r2.y += a2.y; r2.z += a2.z; r2.w += a2.w;
    r3.x += a3.x; r3.y += a3.y; r3.z += a3.z; r3.w += a3.w;
  }
  float* dst = partial + ((long)chunk * 64 + bh) * 4096 + t * 16;
  *reinterpret_cast<float4*>(dst) = r0;
  *reinterpret_cast<float4*>(dst + 4) = r1;
  *reinterpret_cast<float4*>(dst + 8) = r2;
  *reinterpret_cast<float4*>(dst + 12) = r3;
}

__global__ __launch_bounds__(256) void k_kv_reduce(const float* __restrict__ partial,
                                                   float* __restrict__ kv) {
  int i4 = (blockIdx.x * 256 + threadIdx.x) * 4;
  float4 s = make_float4(0.f, 0.f, 0.f, 0.f);
#pragma unroll
  for (int c = 0; c < 8; c++) {
    float4 p = *reinterpret_cast<const float4*>(&partial[(long)c * 262144 + i4]);
    s.x += p.x; s.y += p.y; s.z += p.z; s.w += p.w;
  }
  *reinterpret_cast<float4*>(&kv[i4]) = s;
}

// ---------------- fused weight: FW_b[n][h*64+d] = sum_e kv[b,h][d][e] * ow[n][h*64+e]
__global__ __launch_bounds__(256) void k_fuse_w(const float* __restrict__ kv,
                                                const ushort_t* __restrict__ ow,
                                                ushort_t* __restrict__ qkv) {
  const int nt = blockIdx.x;
  const int h = blockIdx.y;
  const int b = blockIdx.z;
  const int t = threadIdx.x;
  const int nn = t >> 2;
  const int d0 = (t & 3) * 16;
  __shared__ float kvt[64][68];
  __shared__ ushort_t ows[64][68];
  const float* kvsrc = kv + (long)(b * 16 + h) * 4096;
  const int n0 = nt * 64;
#pragma unroll
  for (int rep = 0; rep < 16; rep++) {
    int lin = rep * 256 + t;
    int d = lin >> 6, e = lin & 63;
    kvt[e][d] = kvsrc[d * 64 + e];
  }
#pragma unroll
  for (int rep = 0; rep < 4; rep++) {
    int lin = rep * 256 + t;
    int r = lin >> 4, c4 = (lin & 15) * 4;
    *reinterpret_cast<ushort4*>(&ows[r][c4]) =
        *reinterpret_cast<const ushort4*>(&ow[(long)(n0 + r) * 1024 + h * 64 + c4]);
  }
  __syncthreads();
  float acc[16];
#pragma unroll
  for (int j = 0; j < 16; j++) acc[j] = 0.f;
  for (int e = 0; e < 64; e++) {
    float own = bf2f(ows[nn][e]);
#pragma unroll
    for (int jj = 0; jj < 4; jj++) {
      const float4 kq = *reinterpret_cast<const float4*>(&kvt[e][d0 + jj * 4]);
      acc[jj * 4 + 0] = fmaf(own, kq.x, acc[jj * 4 + 0]);
      acc[jj * 4 + 1] = fmaf(own, kq.y, acc[jj * 4 + 1]);
      acc[jj * 4 + 2] = fmaf(own, kq.z, acc[jj * 4 + 2]);
      acc[jj * 4 + 3] = fmaf(own, kq.w, acc[jj * 4 + 3]);
    }
  }
  ushort_t* dst = qkv + (long)(b * 1024 + n0 + nn) * 3072 + 1024 + h * 64 + d0;
#pragma unroll
  for (int jj = 0; jj < 4; jj++) {
    ushort4 o;
    o.x = f2bf(acc[jj * 4 + 0]); o.y = f2bf(acc[jj * 4 + 1]);
    o.z = f2bf(acc[jj * 4 + 2]); o.w = f2bf(acc[jj * 4 + 3]);
    *reinterpret_cast<ushort4*>(dst + jj * 4) = o;
  }
}

extern "C" void kernel_launch(void* const* d_in, const int* in_sizes, int n_in, void* d_out,
                              int out_size, void* d_ws, size_t ws_size, hipStream_t stream) {
  const float* x   = (const float*)d_in[0];
  const float* q_w = (const float*)d_in[1];
  const float* q_b = (const float*)d_in[2];
  const float* k_w = (const float*)d_in[3];
  const float* k_b = (const float*)d_in[4];
  const float* v_w = (const float*)d_in[5];
  const float* v_b = (const float*)d_in[6];
  const float* o_w = (const float*)d_in[7];
  const float* o_b = (const float*)d_in[8];
  float* out = (float*)d_out;

  char* ws = (char*)d_ws;
  ushort_t* xb    = (ushort_t*)(ws);              // 33,554,432  x as bf16
  ushort_t* wqkv  = (ushort_t*)(ws + 33554432);   //  6,291,456  [q_w;k_w;v_w] bf16
  ushort_t* owb   = (ushort_t*)(ws + 39845888);   //  2,097,152  o_w bf16 (wqkv+3*1M elems)
  float*    biasq = (float*)(ws + 41943040);      //     12,288  [q_b;k_b;v_b]
  ushort_t* qkv   = (ushort_t*)(ws + 41955328);   // 100,663,296 [M][3072] bf16
  float* partial = (float*)(ws);                  //  8,388,608  [8][64][4096] (recycles xb)
  float* kvbuf   = (float*)(ws + 33554432);       //  1,048,576  (recycles wqkv)

  // all packs in one launch: x (8192 blks) + weights (4096, dst wqkv..owb contiguous) + bias (12)
  k_pack_all<<<12300, 256, 0, stream>>>(x, q_w, k_w, v_w, o_w, q_b, k_b, v_b, xb, wqkv, biasq);

  // QKV projection: [16384 x 1024] x [3072 x 1024]^T (+bias, relu on cols<2048)
  k_gemm128<false><<<dim3(24, 128, 1), 512, 0, stream>>>(xb, 1024, 0, wqkv, 1024, 0,
                                                         biasq, 2048, qkv, 3072, 0, 1024);
  // KV state
  k_kv_partial<<<dim3(64, 8), 256, 0, stream>>>(qkv, partial);
  k_kv_reduce<<<256, 256, 0, stream>>>(partial, kvbuf);
  // fold KV into o_w (per-batch fused weight in dead k-columns of qkv rows 0..4095)
  k_fuse_w<<<dim3(16, 16, 4), 256, 0, stream>>>(kvbuf, owb, qkv);
  // out_b = relu(q)_b @ FW_b^T + o_b  — single batched launch (grid.z = 4)
  k_gemm128<true><<<dim3(8, 32, 4), 512, 0, stream>>>(
      qkv, 3072, (long)4096 * 3072, qkv + 1024, 3072, (long)1024 * 3072,
      o_b, 0, out, 1024, (long)4096 * 1024, 1024);
}

// Round 13
// 227.943 us; speedup vs baseline: 1.0439x; 1.0439x over previous
//
#include <hip/hip_runtime.h>

typedef unsigned short ushort_t;
typedef __attribute__((ext_vector_type(8))) __bf16 bf16x8;
typedef __attribute__((ext_vector_type(8))) unsigned short us8;
typedef __attribute__((ext_vector_type(4))) float f32x4;

// async global->LDS, 16B per lane. LDS dest is wave-uniform base + lane*16 (m97/m104).
#define GLOAD_LDS16(gp, lp)                                                              \
  __builtin_amdgcn_global_load_lds(                                                     \
      (const __attribute__((address_space(1))) unsigned int*)(gp),                      \
      (__attribute__((address_space(3))) unsigned int*)(lp), 16, 0, 0)

#define MEMFENCE() asm volatile("" ::: "memory")
#define SBARRIER()                          \
  do {                                      \
    MEMFENCE();                             \
    __builtin_amdgcn_s_barrier();           \
    MEMFENCE();                             \
  } while (0)
#define WAIT_VM2() asm volatile("s_waitcnt vmcnt(2)" ::: "memory")
#define WAIT_VM0() asm volatile("s_waitcnt vmcnt(0)" ::: "memory")
#define WAIT_LGKM0P() asm volatile("s_waitcnt lgkmcnt(0)" ::: "memory")
#define WAIT_LGKM8() asm volatile("s_waitcnt lgkmcnt(8)" ::: "memory")

__device__ __forceinline__ ushort_t f2bf(float f) {
  unsigned u = __builtin_bit_cast(unsigned, f);
  u += 0x7fffu + ((u >> 16) & 1u);  // RNE
  return (ushort_t)(u >> 16);
}
__device__ __forceinline__ float bf2f(ushort_t h) {
  return __builtin_bit_cast(float, (unsigned)h << 16);
}

// ---------------- merged pack: x (8 elems/thr, 16B stores) + w4 + bias, one launch ----
__global__ __launch_bounds__(256) void k_pack_all(
    const float* __restrict__ x, const float* __restrict__ q_w,
    const float* __restrict__ k_w, const float* __restrict__ v_w,
    const float* __restrict__ o_w, const float* __restrict__ q_b,
    const float* __restrict__ k_b, const float* __restrict__ v_b,
    ushort_t* __restrict__ xb, ushort_t* __restrict__ wdst, float* __restrict__ biasq) {
  const int blk = blockIdx.x;
  if (blk < 8192) {  // x: 16,777,216 elems = 8192 blocks x 256 thr x 8
    long i = ((long)blk * 256 + threadIdx.x) * 8;
    float4 a = *reinterpret_cast<const float4*>(x + i);
    float4 b = *reinterpret_cast<const float4*>(x + i + 4);
    us8 o;
    o[0] = f2bf(a.x); o[1] = f2bf(a.y); o[2] = f2bf(a.z); o[3] = f2bf(a.w);
    o[4] = f2bf(b.x); o[5] = f2bf(b.y); o[6] = f2bf(b.z); o[7] = f2bf(b.w);
    *reinterpret_cast<us8*>(xb + i) = o;
  } else if (blk < 12288) {  // weights: 4096 blocks
    const int wb = blk - 8192;
    const int wsel = wb >> 10;
    const float* src = wsel == 0 ? q_w : wsel == 1 ? k_w : wsel == 2 ? v_w : o_w;
    const int off = (wb & 1023) * 1024 + threadIdx.x * 4;
    float4 v = *reinterpret_cast<const float4*>(src + off);
    ushort4 o;
    o.x = f2bf(v.x); o.y = f2bf(v.y); o.z = f2bf(v.z); o.w = f2bf(v.w);
    *reinterpret_cast<ushort4*>(wdst + wsel * 1048576 + off) = o;
  } else {  // bias: 12 blocks -> 3072
    int i = (blk - 12288) * 256 + threadIdx.x;
    const float* s = i < 1024 ? q_b : (i < 2048 ? k_b : v_b);
    biasq[i] = s[i & 1023];
  }
}

// ---------------- 256x256 8-phase GEMM (R6/R9 schedule — best measured: 103.4 µs, 43%)
// C[m][n] = sum_k A[m][k]*Bw[n][k] + bias[n], relu if n < relu_lim.
// LDS: buf(2) x op(A,B) x half(2) slots of [128][64] bf16 (16 KiB each) = 128 KiB.
// T2 swizzle (G4): read byte = row*128 + (kbyte ^ ((row&7)<<4)); LDS dest linear,
// inverse swizzle on GLOBAL source k-unit (rule #21). Bank-conflict = 0 (R4 PMC).
// 1 barrier/phase (except post-P4/P8 vmcnt points); 12/4/8 read split + lgkm pacing.
// A/B history: R5 2-bar/phase = slower; R7 read-early = -38%; R10 stage-bunch = -4%;
// R12 128^2-tile 2blk/CU = -16% (FETCH 3x, HBM-bound). CONVERGED — do not modify.

__device__ __forceinline__ void stage_half(const ushort_t* __restrict__ g, int ld, int kt,
                                           ushort_t* slot, int w, int lane) {
  const int swz = ((lane & 7) ^ (lane >> 3)) * 8;  // inverse st swizzle on source (elems)
#pragma unroll
  for (int l = 0; l < 2; l++) {
    int row = l * 64 + w * 8 + (lane >> 3);
    GLOAD_LDS16(g + (long)row * ld + kt + swz, slot + l * 4096 + w * 512);
  }
}

__device__ __forceinline__ bf16x8 read_frag(const ushort_t* slot, int row, int kbyte) {
  int byte = row * 128 + (kbyte ^ ((row & 7) << 4));  // 3-bit XOR: 8-slot spread
  return *reinterpret_cast<const bf16x8*>(reinterpret_cast<const char*>(slot) + byte);
}

template <bool OUT_F32>
__global__ __launch_bounds__(512, 2) void k_gemm256(
    const ushort_t* __restrict__ A, int lda, long strideA,
    const ushort_t* __restrict__ Bw, int ldb, long strideB,
    const float* __restrict__ bias, int relu_lim,
    void* __restrict__ Cout, int ldc, long strideC, int K) {
  __shared__ ushort_t lds[65536];  // 128 KiB
  const int t = threadIdx.x;
  const int lane = t & 63;
  const int w = t >> 6;
  const int wm = w >> 2, wn = w & 3;
  const int z = blockIdx.z;

  // XCD-aware swizzle (nwg % 8 == 0 in all our launches -> simple form bijective)
  const int nx = gridDim.x;
  const int nwg = nx * gridDim.y;
  const int lin = blockIdx.x + blockIdx.y * nx;
  const int q8 = nwg >> 3;
  const int s = (lin & 7) * q8 + (lin >> 3);
  const long rowBase = (long)(s / nx) * 256;
  const long colBase = (long)(s % nx) * 256;

  const ushort_t* Ap = A + z * strideA + rowBase * lda;
  const ushort_t* Bp = Bw + z * strideB + colBase * ldb;

#define SLOT(buf, isB, half) (lds + (buf) * 32768 + (isB) * 16384 + (half) * 8192)
#define STAGE(gb, ld, kt, buf, isB, half) stage_half((gb), (ld), (kt), SLOT(buf, isB, half), w, lane)

  f32x4 acc[8][4];
#pragma unroll
  for (int mi = 0; mi < 8; mi++)
#pragma unroll
    for (int ni = 0; ni < 4; ni++) acc[mi][ni] = (f32x4){0.f, 0.f, 0.f, 0.f};
  bf16x8 Ar[4][2], Br[4][2];
  const int fr = lane & 15;
  const int kb = (lane >> 4) * 16;  // byte offset within 64-elem k (per ks add ks*64)

#define LOADA(buf, miB)                                                             \
  do {                                                                              \
    const ushort_t* sl = SLOT(buf, 0, wm);                                          \
    _Pragma("unroll") for (int mi = 0; mi < 4; mi++)                                \
        _Pragma("unroll") for (int ks = 0; ks < 2; ks++)                            \
            Ar[mi][ks] = read_frag(sl, (miB + mi) * 16 + fr, ks * 64 + kb);         \
  } while (0)
#define LOADB(buf, ns)                                                              \
  do {                                                                              \
    const ushort_t* sl = SLOT(buf, 1, wn >> 1);                                     \
    _Pragma("unroll") for (int nj = 0; nj < 2; nj++)                                \
        _Pragma("unroll") for (int ks = 0; ks < 2; ks++)                            \
            Br[(ns) * 2 + nj][ks] =                                                 \
                read_frag(sl, (wn & 1) * 64 + ((ns) * 2 + nj) * 16 + fr, ks * 64 + kb); \
  } while (0)
#define MFMA16(miB, ns)                                                             \
  do {                                                                              \
    _Pragma("unroll") for (int ks = 0; ks < 2; ks++)                                \
        _Pragma("unroll") for (int mi = 0; mi < 4; mi++)                            \
            _Pragma("unroll") for (int nj = 0; nj < 2; nj++)                        \
                acc[(miB) + mi][(ns) * 2 + nj] = __builtin_amdgcn_mfma_f32_16x16x32_bf16( \
                    Ar[mi][ks], Br[(ns) * 2 + nj][ks], acc[(miB) + mi][(ns) * 2 + nj], 0, 0, 0); \
  } while (0)

  const ushort_t* Ap1 = Ap + 128 * (long)lda;
  const ushort_t* Bp1 = Bp + 128 * (long)ldb;

  // Prologue: tile0 (A0,B0,A1,B1 -> buf0) + tile1.A0 -> buf1; drain tile0.
  STAGE(Ap, lda, 0, 0, 0, 0);
  STAGE(Bp, ldb, 0, 0, 1, 0);
  STAGE(Ap1, lda, 0, 0, 0, 1);
  STAGE(Bp1, ldb, 0, 0, 1, 1);
  STAGE(Ap, lda, 64, 1, 0, 0);
  WAIT_VM2();
  SBARRIER();

  const int NT2 = K >> 7;  // K/128, 2 K-tiles per iteration
  for (int it = 0; it < NT2; it++) {
    const int kt = it << 7;
    const int ktb = kt + 64;
    const int ktn = (kt + 128 < K) ? kt + 128 : K - 64;   // clamped re-stage: duplicate bytes, benign
    const int ktn2 = (kt + 192 < K) ? kt + 192 : K - 64;

    // P1: reads buf0 A[m0-3]+B[n0-1] (12 ds_read); stage (t+1).B0 -> buf1
    LOADA(0, 0); LOADB(0, 0);
    STAGE(Bp, ldb, ktb, 1, 1, 0);
    WAIT_LGKM8();
    SBARRIER();
    WAIT_LGKM0P();
    __builtin_amdgcn_s_setprio(1); MFMA16(0, 0); __builtin_amdgcn_s_setprio(0);
    // P2: reads buf0 B[n2-3]; stage (t+1).A1 -> buf1
    LOADB(0, 1);
    STAGE(Ap1, lda, ktb, 1, 0, 1);
    SBARRIER();
    WAIT_LGKM0P();
    __builtin_amdgcn_s_setprio(1); MFMA16(0, 1); __builtin_amdgcn_s_setprio(0);
    // P3: reads buf0 A[m4-7]; stage (t+1).B1 -> buf1
    LOADA(0, 4);
    STAGE(Bp1, ldb, ktb, 1, 1, 1);
    SBARRIER();
    WAIT_LGKM0P();
    __builtin_amdgcn_s_setprio(1); MFMA16(4, 0); __builtin_amdgcn_s_setprio(0);
    // P4: no reads; stage (t+2).A0 -> buf0; drain all but newest stage
    STAGE(Ap, lda, ktn, 0, 0, 0);
    SBARRIER();
    __builtin_amdgcn_s_setprio(1); MFMA16(4, 1); __builtin_amdgcn_s_setprio(0);
    WAIT_VM2();
    SBARRIER();
    // P5: reads buf1 A[m0-3]+B[n0-1]; stage (t+2).B0 -> buf0
    LOADA(1, 0); LOADB(1, 0);
    STAGE(Bp, ldb, ktn, 0, 1, 0);
    WAIT_LGKM8();
    SBARRIER();
    WAIT_LGKM0P();
    __builtin_amdgcn_s_setprio(1); MFMA16(0, 0); __builtin_amdgcn_s_setprio(0);
    // P6: reads buf1 B[n2-3]; stage (t+2).A1 -> buf0
    LOADB(1, 1);
    STAGE(Ap1, lda, ktn, 0, 0, 1);
    SBARRIER();
    WAIT_LGKM0P();
    __builtin_amdgcn_s_setprio(1); MFMA16(0, 1); __builtin_amdgcn_s_setprio(0);
    // P7: reads buf1 A[m4-7]; stage (t+2).B1 -> buf0
    LOADA(1, 4);
    STAGE(Bp1, ldb, ktn, 0, 1, 1);
    SBARRIER();
    WAIT_LGKM0P();
    __builtin_amdgcn_s_setprio(1); MFMA16(4, 0); __builtin_amdgcn_s_setprio(0);
    // P8: stage (t+3).A0 -> buf1; drain all but newest stage
    STAGE(Ap, lda, ktn2, 1, 0, 0);
    SBARRIER();
    __builtin_amdgcn_s_setprio(1); MFMA16(4, 1); __builtin_amdgcn_s_setprio(0);
    WAIT_VM2();
    SBARRIER();
  }

  // ---- Epilogue: drain in-flight stages, then per-wave LDS transpose -> 16B stores.
  WAIT_VM0();
  SBARRIER();
  {
    float* sl = reinterpret_cast<float*>(lds) + w * 2048;  // 8 KiB per wave; [16][68] f32
    const int rowQ = (lane >> 4) * 4;
    float bv[4];
#pragma unroll
    for (int ni = 0; ni < 4; ni++) bv[ni] = bias[(int)colBase + wn * 64 + ni * 16 + fr];
    const int rr = lane >> 2;        // 0..15: readback row
    const int cq = (lane & 3) * 16;  // 0..48: readback col quad
#pragma unroll
    for (int mi = 0; mi < 8; mi++) {
#pragma unroll
      for (int ni = 0; ni < 4; ni++) {
        const bool doRelu = ((int)colBase + wn * 64 + ni * 16 + fr) < relu_lim;
#pragma unroll
        for (int r = 0; r < 4; r++) {
          float v = acc[mi][ni][r] + bv[ni];
          if (doRelu) v = fmaxf(v, 0.f);
          sl[(rowQ + r) * 68 + ni * 16 + fr] = v;
        }
      }
      asm volatile("s_waitcnt lgkmcnt(0)" ::: "memory");
      __builtin_amdgcn_sched_barrier(0);
      float4 v0 = *reinterpret_cast<const float4*>(&sl[rr * 68 + cq]);
      float4 v1 = *reinterpret_cast<const float4*>(&sl[rr * 68 + cq + 4]);
      float4 v2 = *reinterpret_cast<const float4*>(&sl[rr * 68 + cq + 8]);
      float4 v3 = *reinterpret_cast<const float4*>(&sl[rr * 68 + cq + 12]);
      const long row = rowBase + wm * 128 + mi * 16 + rr;
      const long gc = colBase + wn * 64 + cq;
      if (OUT_F32) {
        float* dst = (float*)Cout + z * strideC + row * (long)ldc + gc;
        *reinterpret_cast<float4*>(dst) = v0;
        *reinterpret_cast<float4*>(dst + 4) = v1;
        *reinterpret_cast<float4*>(dst + 8) = v2;
        *reinterpret_cast<float4*>(dst + 12) = v3;
      } else {
        ushort_t* dst = (ushort_t*)Cout + z * strideC + row * (long)ldc + gc;
        us8 o0, o1;
        o0[0] = f2bf(v0.x); o0[1] = f2bf(v0.y); o0[2] = f2bf(v0.z); o0[3] = f2bf(v0.w);
        o0[4] = f2bf(v1.x); o0[5] = f2bf(v1.y); o0[6] = f2bf(v1.z); o0[7] = f2bf(v1.w);
        o1[0] = f2bf(v2.x); o1[1] = f2bf(v2.y); o1[2] = f2bf(v2.z); o1[3] = f2bf(v2.w);
        o1[4] = f2bf(v3.x); o1[5] = f2bf(v3.y); o1[6] = f2bf(v3.z); o1[7] = f2bf(v3.w);
        *reinterpret_cast<us8*>(dst) = o0;
        *reinterpret_cast<us8*>(dst + 8) = o1;
      }
      asm volatile("s_waitcnt lgkmcnt(0)" ::: "memory");  // reads retired before next mi overwrite
    }
  }
#undef SLOT
#undef STAGE
#undef LOADA
#undef LOADB
#undef MFMA16
}

// ---------------- KV state partials: [8][64][64][64], 4-wave blocks, LDS block-reduce --
__global__ __launch_bounds__(256) void k_kv_partial(const ushort_t* __restrict__ qkv,
                                                    float* __restrict__ partial) {
  const int bh = blockIdx.x;     // 0..63
  const int chunk = blockIdx.y;  // 0..7
  const int b = bh >> 4, h = bh & 15;
  const int t = threadIdx.x;
  const int w = t >> 6, lane = t & 63;
  const int d0 = (lane >> 2) * 4;
  const int e0 = (lane & 3) * 16;
  __shared__ float smem[16384];  // 64 KiB: per-wave staging (32K), then reduce (64K)
  float* kk = smem + w * 2048;         // [16][64]
  float* vv = smem + w * 2048 + 1024;  // [16][64]
  float acc[4][16];
#pragma unroll
  for (int di = 0; di < 4; di++)
#pragma unroll
    for (int j = 0; j < 16; j++) acc[di][j] = 0.f;

  const long rowbase = (long)b * 4096 + (long)chunk * 512 + (long)w * 128;
  for (int itr = 0; itr < 8; itr++) {
    __syncthreads();
#pragma unroll
    for (int rep = 0; rep < 4; rep++) {
      int lin = rep * 64 + lane;        // 0..255
      int op = lin >> 7;                // reps 0,1 -> k; reps 2,3 -> v
      int r = (lin >> 3) & 15;
      int c8 = (lin & 7) * 8;
      long m = rowbase + itr * 16 + r;
      us8 u = *reinterpret_cast<const us8*>(&qkv[m * 3072 + (op ? 2048 : 1024) + h * 64 + c8]);
      float* dst = (op ? vv : kk) + r * 64 + c8;
      float4 lo = {bf2f(u[0]), bf2f(u[1]), bf2f(u[2]), bf2f(u[3])};
      float4 hi = {bf2f(u[4]), bf2f(u[5]), bf2f(u[6]), bf2f(u[7])};
      *reinterpret_cast<float4*>(dst) = lo;
      *reinterpret_cast<float4*>(dst + 4) = hi;
    }
    __syncthreads();
#pragma unroll
    for (int ss = 0; ss < 16; ss++) {
      const float4 kq = *reinterpret_cast<const float4*>(&kk[ss * 64 + d0]);
#pragma unroll
      for (int jj = 0; jj < 4; jj++) {
        const float4 vq = *reinterpret_cast<const float4*>(&vv[ss * 64 + e0 + jj * 4]);
        acc[0][jj * 4 + 0] = fmaf(kq.x, vq.x, acc[0][jj * 4 + 0]);
        acc[0][jj * 4 + 1] = fmaf(kq.x, vq.y, acc[0][jj * 4 + 1]);
        acc[0][jj * 4 + 2] = fmaf(kq.x, vq.z, acc[0][jj * 4 + 2]);
        acc[0][jj * 4 + 3] = fmaf(kq.x, vq.w, acc[0][jj * 4 + 3]);
        acc[1][jj * 4 + 0] = fmaf(kq.y, vq.x, acc[1][jj * 4 + 0]);
        acc[1][jj * 4 + 1] = fmaf(kq.y, vq.y, acc[1][jj * 4 + 1]);
        acc[1][jj * 4 + 2] = fmaf(kq.y, vq.z, acc[1][jj * 4 + 2]);
        acc[1][jj * 4 + 3] = fmaf(kq.y, vq.w, acc[1][jj * 4 + 3]);
        acc[2][jj * 4 + 0] = fmaf(kq.z, vq.x, acc[2][jj * 4 + 0]);
        acc[2][jj * 4 + 1] = fmaf(kq.z, vq.y, acc[2][jj * 4 + 1]);
        acc[2][jj * 4 + 2] = fmaf(kq.z, vq.z, acc[2][jj * 4 + 2]);
        acc[2][jj * 4 + 3] = fmaf(kq.z, vq.w, acc[2][jj * 4 + 3]);
        acc[3][jj * 4 + 0] = fmaf(kq.w, vq.x, acc[3][jj * 4 + 0]);
        acc[3][jj * 4 + 1] = fmaf(kq.w, vq.y, acc[3][jj * 4 + 1]);
        acc[3][jj * 4 + 2] = fmaf(kq.w, vq.z, acc[3][jj * 4 + 2]);
        acc[3][jj * 4 + 3] = fmaf(kq.w, vq.w, acc[3][jj * 4 + 3]);
      }
    }
  }
  // block reduce: waves write acc to LDS, then each thread sums 16 outputs across waves
  __syncthreads();
#pragma unroll
  for (int di = 0; di < 4; di++)
#pragma unroll
    for (int j4 = 0; j4 < 4; j4++)
      *reinterpret_cast<float4*>(&smem[(w * 64 + lane) * 64 + di * 16 + j4 * 4]) =
          make_float4(acc[di][j4 * 4], acc[di][j4 * 4 + 1], acc[di][j4 * 4 + 2],
                      acc[di][j4 * 4 + 3]);
  __syncthreads();
  const int u = (t >> 4) * 4 + (t & 3);  // owner lane of (d,e) block
  const int di = (t >> 2) & 3;
  float4 r0 = {0, 0, 0, 0}, r1 = {0, 0, 0, 0}, r2 = {0, 0, 0, 0}, r3 = {0, 0, 0, 0};
#pragma unroll
  for (int ww = 0; ww < 4; ww++) {
    const float* base = &smem[(ww * 64 + u) * 64 + di * 16];
    float4 a0 = *reinterpret_cast<const float4*>(base);
    float4 a1 = *reinterpret_cast<const float4*>(base + 4);
    float4 a2 = *reinterpret_cast<const float4*>(base + 8);
    float4 a3 = *reinterpret_cast<const float4*>(base + 12);
    r0.x += a0.x; r0.y += a0.y; r0.z += a0.z; r0.w += a0.w;
    r1.x += a1.x; r1.y += a1.y; r1.z += a1.z; r1.w += a1.w;
    r2.x += a2.x; r2.y += a2.y; r2.z += a2.z; r2.w += a2.w;
    r3.x += a3.x; r3.y += a3.y; r3.z += a3.z; r3.w += a3.w;
  }
  float* dst = partial + ((long)chunk * 64 + bh) * 4096 + t * 16;
  *reinterpret_cast<float4*>(dst) = r0;
  *reinterpret_cast<float4*>(dst + 4) = r1;
  *reinterpret_cast<float4*>(dst + 8) = r2;
  *reinterpret_cast<float4*>(dst + 12) = r3;
}

__global__ __launch_bounds__(256) void k_kv_reduce(const float* __restrict__ partial,
                                                   float* __restrict__ kv) {
  int i4 = (blockIdx.x * 256 + threadIdx.x) * 4;
  float4 s = make_float4(0.f, 0.f, 0.f, 0.f);
#pragma unroll
  for (int c = 0; c < 8; c++) {
    float4 p = *reinterpret_cast<const float4*>(&partial[(long)c * 262144 + i4]);
    s.x += p.x; s.y += p.y; s.z += p.z; s.w += p.w;
  }
  *reinterpret_cast<float4*>(&kv[i4]) = s;
}

// ---------------- fused weight: FW_b[n][h*64+d] = sum_e kv[b,h][d][e] * ow[n][h*64+e]
__global__ __launch_bounds__(256) void k_fuse_w(const float* __restrict__ kv,
                                                const ushort_t* __restrict__ ow,
                                                ushort_t* __restrict__ qkv) {
  const int nt = blockIdx.x;
  const int h = blockIdx.y;
  const int b = blockIdx.z;
  const int t = threadIdx.x;
  const int nn = t >> 2;
  const int d0 = (t & 3) * 16;
  __shared__ float kvt[64][68];
  __shared__ ushort_t ows[64][68];
  const float* kvsrc = kv + (long)(b * 16 + h) * 4096;
  const int n0 = nt * 64;
#pragma unroll
  for (int rep = 0; rep < 16; rep++) {
    int lin = rep * 256 + t;
    int d = lin >> 6, e = lin & 63;
    kvt[e][d] = kvsrc[d * 64 + e];
  }
#pragma unroll
  for (int rep = 0; rep < 4; rep++) {
    int lin = rep * 256 + t;
    int r = lin >> 4, c4 = (lin & 15) * 4;
    *reinterpret_cast<ushort4*>(&ows[r][c4]) =
        *reinterpret_cast<const ushort4*>(&ow[(long)(n0 + r) * 1024 + h * 64 + c4]);
  }
  __syncthreads();
  float acc[16];
#pragma unroll
  for (int j = 0; j < 16; j++) acc[j] = 0.f;
  for (int e = 0; e < 64; e++) {
    float own = bf2f(ows[nn][e]);
#pragma unroll
    for (int jj = 0; jj < 4; jj++) {
      const float4 kq = *reinterpret_cast<const float4*>(&kvt[e][d0 + jj * 4]);
      acc[jj * 4 + 0] = fmaf(own, kq.x, acc[jj * 4 + 0]);
      acc[jj * 4 + 1] = fmaf(own, kq.y, acc[jj * 4 + 1]);
      acc[jj * 4 + 2] = fmaf(own, kq.z, acc[jj * 4 + 2]);
      acc[jj * 4 + 3] = fmaf(own, kq.w, acc[jj * 4 + 3]);
    }
  }
  ushort_t* dst = qkv + (long)(b * 1024 + n0 + nn) * 3072 + 1024 + h * 64 + d0;
#pragma unroll
  for (int jj = 0; jj < 4; jj++) {
    ushort4 o;
    o.x = f2bf(acc[jj * 4 + 0]); o.y = f2bf(acc[jj * 4 + 1]);
    o.z = f2bf(acc[jj * 4 + 2]); o.w = f2bf(acc[jj * 4 + 3]);
    *reinterpret_cast<ushort4*>(dst + jj * 4) = o;
  }
}

extern "C" void kernel_launch(void* const* d_in, const int* in_sizes, int n_in, void* d_out,
                              int out_size, void* d_ws, size_t ws_size, hipStream_t stream) {
  const float* x   = (const float*)d_in[0];
  const float* q_w = (const float*)d_in[1];
  const float* q_b = (const float*)d_in[2];
  const float* k_w = (const float*)d_in[3];
  const float* k_b = (const float*)d_in[4];
  const float* v_w = (const float*)d_in[5];
  const float* v_b = (const float*)d_in[6];
  const float* o_w = (const float*)d_in[7];
  const float* o_b = (const float*)d_in[8];
  float* out = (float*)d_out;

  char* ws = (char*)d_ws;
  ushort_t* xb    = (ushort_t*)(ws);              // 33,554,432  x as bf16
  ushort_t* wqkv  = (ushort_t*)(ws + 33554432);   //  6,291,456  [q_w;k_w;v_w] bf16
  ushort_t* owb   = (ushort_t*)(ws + 39845888);   //  2,097,152  o_w bf16 (wqkv+3*1M elems)
  float*    biasq = (float*)(ws + 41943040);      //     12,288  [q_b;k_b;v_b]
  ushort_t* qkv   = (ushort_t*)(ws + 41955328);   // 100,663,296 [M][3072] bf16
  float* partial = (float*)(ws);                  //  8,388,608  [8][64][4096] (recycles xb)
  float* kvbuf   = (float*)(ws + 33554432);       //  1,048,576  (recycles wqkv)

  // all packs in one launch: x (8192 blks) + weights (4096, dst wqkv..owb contiguous) + bias (12)
  k_pack_all<<<12300, 256, 0, stream>>>(x, q_w, k_w, v_w, o_w, q_b, k_b, v_b, xb, wqkv, biasq);

  // QKV projection: [16384 x 1024] x [3072 x 1024]^T (+bias, relu on cols<2048)
  k_gemm256<false><<<dim3(12, 64, 1), 512, 0, stream>>>(xb, 1024, 0, wqkv, 1024, 0,
                                                        biasq, 2048, qkv, 3072, 0, 1024);
  // KV state
  k_kv_partial<<<dim3(64, 8), 256, 0, stream>>>(qkv, partial);
  k_kv_reduce<<<256, 256, 0, stream>>>(partial, kvbuf);
  // fold KV into o_w (per-batch fused weight in dead k-columns of qkv rows 0..4095)
  k_fuse_w<<<dim3(16, 16, 4), 256, 0, stream>>>(kvbuf, owb, qkv);
  // out_b = relu(q)_b @ FW_b^T + o_b  — single batched launch (grid.z = 4)
  k_gemm256<true><<<dim3(4, 16, 4), 512, 0, stream>>>(
      qkv, 3072, (long)4096 * 3072, qkv + 1024, 3072, (long)1024 * 3072,
      o_b, 0, out, 1024, (long)4096 * 1024, 1024);
}

// Round 14
// 226.470 us; speedup vs baseline: 1.0507x; 1.0065x over previous
//
#include <hip/hip_runtime.h>

typedef unsigned short ushort_t;
typedef __attribute__((ext_vector_type(8))) __bf16 bf16x8;
typedef __attribute__((ext_vector_type(8))) unsigned short us8;
typedef __attribute__((ext_vector_type(4))) float f32x4;

// async global->LDS, 16B per lane. LDS dest is wave-uniform base + lane*16 (m97/m104).
#define GLOAD_LDS16(gp, lp)                                                              \
  __builtin_amdgcn_global_load_lds(                                                     \
      (const __attribute__((address_space(1))) unsigned int*)(gp),                      \
      (__attribute__((address_space(3))) unsigned int*)(lp), 16, 0, 0)

#define MEMFENCE() asm volatile("" ::: "memory")
#define SBARRIER()                          \
  do {                                      \
    MEMFENCE();                             \
    __builtin_amdgcn_s_barrier();           \
    MEMFENCE();                             \
  } while (0)
#define WAIT_VM2() asm volatile("s_waitcnt vmcnt(2)" ::: "memory")
#define WAIT_VM0() asm volatile("s_waitcnt vmcnt(0)" ::: "memory")
#define WAIT_LGKM0P() asm volatile("s_waitcnt lgkmcnt(0)" ::: "memory")
#define WAIT_LGKM8() asm volatile("s_waitcnt lgkmcnt(8)" ::: "memory")

__device__ __forceinline__ ushort_t f2bf(float f) {
  unsigned u = __builtin_bit_cast(unsigned, f);
  u += 0x7fffu + ((u >> 16) & 1u);  // RNE
  return (ushort_t)(u >> 16);
}
__device__ __forceinline__ float bf2f(ushort_t h) {
  return __builtin_bit_cast(float, (unsigned)h << 16);
}

// ---------------- merged pack: x (8 elems/thr, 16B stores) + w4 + bias, one launch ----
__global__ __launch_bounds__(256) void k_pack_all(
    const float* __restrict__ x, const float* __restrict__ q_w,
    const float* __restrict__ k_w, const float* __restrict__ v_w,
    const float* __restrict__ o_w, const float* __restrict__ q_b,
    const float* __restrict__ k_b, const float* __restrict__ v_b,
    ushort_t* __restrict__ xb, ushort_t* __restrict__ wdst, float* __restrict__ biasq) {
  const int blk = blockIdx.x;
  if (blk < 8192) {  // x: 16,777,216 elems = 8192 blocks x 256 thr x 8
    long i = ((long)blk * 256 + threadIdx.x) * 8;
    float4 a = *reinterpret_cast<const float4*>(x + i);
    float4 b = *reinterpret_cast<const float4*>(x + i + 4);
    us8 o;
    o[0] = f2bf(a.x); o[1] = f2bf(a.y); o[2] = f2bf(a.z); o[3] = f2bf(a.w);
    o[4] = f2bf(b.x); o[5] = f2bf(b.y); o[6] = f2bf(b.z); o[7] = f2bf(b.w);
    *reinterpret_cast<us8*>(xb + i) = o;
  } else if (blk < 12288) {  // weights: 4096 blocks
    const int wb = blk - 8192;
    const int wsel = wb >> 10;
    const float* src = wsel == 0 ? q_w : wsel == 1 ? k_w : wsel == 2 ? v_w : o_w;
    const int off = (wb & 1023) * 1024 + threadIdx.x * 4;
    float4 v = *reinterpret_cast<const float4*>(src + off);
    ushort4 o;
    o.x = f2bf(v.x); o.y = f2bf(v.y); o.z = f2bf(v.z); o.w = f2bf(v.w);
    *reinterpret_cast<ushort4*>(wdst + wsel * 1048576 + off) = o;
  } else {  // bias: 12 blocks -> 3072
    int i = (blk - 12288) * 256 + threadIdx.x;
    const float* s = i < 1024 ? q_b : (i < 2048 ? k_b : v_b);
    biasq[i] = s[i & 1023];
  }
}

// ---------------- 256x256 8-phase GEMM (R6/R9 schedule + R14 P4/P8 barrier merge) ----
// C[m][n] = sum_k A[m][k]*Bw[n][k] + bias[n], relu if n < relu_lim.
// LDS: buf(2) x op(A,B) x half(2) slots of [128][64] bf16 (16 KiB each) = 128 KiB.
// T2 swizzle (G4): read byte = row*128 + (kbyte ^ ((row&7)<<4)); LDS dest linear,
// inverse swizzle on GLOBAL source k-unit (rule #21). Bank-conflict = 0 (R4 PMC).
// R14: P4/P8 use ONE barrier: STAGE -> vmcnt(2) -> barrier -> MFMA (reg-only).
// vmcnt(2) pre-barrier still guarantees tile T+1 fully landed for all waves before
// any wave reads it (P5/P1-next). Saves 2 of 10 barriers/iter.
// A/B history: R5 2-bar/phase slower; R7 read-early -38%; R10 stage-bunch -4%;
// R12 128^2 2blk/CU -16% (traffic-bound).

__device__ __forceinline__ void stage_half(const ushort_t* __restrict__ g, int ld, int kt,
                                           ushort_t* slot, int w, int lane) {
  const int swz = ((lane & 7) ^ (lane >> 3)) * 8;  // inverse st swizzle on source (elems)
#pragma unroll
  for (int l = 0; l < 2; l++) {
    int row = l * 64 + w * 8 + (lane >> 3);
    GLOAD_LDS16(g + (long)row * ld + kt + swz, slot + l * 4096 + w * 512);
  }
}

__device__ __forceinline__ bf16x8 read_frag(const ushort_t* slot, int row, int kbyte) {
  int byte = row * 128 + (kbyte ^ ((row & 7) << 4));  // 3-bit XOR: 8-slot spread
  return *reinterpret_cast<const bf16x8*>(reinterpret_cast<const char*>(slot) + byte);
}

template <bool OUT_F32>
__global__ __launch_bounds__(512, 2) void k_gemm256(
    const ushort_t* __restrict__ A, int lda, long strideA,
    const ushort_t* __restrict__ Bw, int ldb, long strideB,
    const float* __restrict__ bias, int relu_lim,
    void* __restrict__ Cout, int ldc, long strideC, int K) {
  __shared__ ushort_t lds[65536];  // 128 KiB
  const int t = threadIdx.x;
  const int lane = t & 63;
  const int w = t >> 6;
  const int wm = w >> 2, wn = w & 3;
  const int z = blockIdx.z;

  // XCD-aware swizzle (nwg % 8 == 0 in all our launches -> simple form bijective)
  const int nx = gridDim.x;
  const int nwg = nx * gridDim.y;
  const int lin = blockIdx.x + blockIdx.y * nx;
  const int q8 = nwg >> 3;
  const int s = (lin & 7) * q8 + (lin >> 3);
  const long rowBase = (long)(s / nx) * 256;
  const long colBase = (long)(s % nx) * 256;

  const ushort_t* Ap = A + z * strideA + rowBase * lda;
  const ushort_t* Bp = Bw + z * strideB + colBase * ldb;

#define SLOT(buf, isB, half) (lds + (buf) * 32768 + (isB) * 16384 + (half) * 8192)
#define STAGE(gb, ld, kt, buf, isB, half) stage_half((gb), (ld), (kt), SLOT(buf, isB, half), w, lane)

  f32x4 acc[8][4];
#pragma unroll
  for (int mi = 0; mi < 8; mi++)
#pragma unroll
    for (int ni = 0; ni < 4; ni++) acc[mi][ni] = (f32x4){0.f, 0.f, 0.f, 0.f};
  bf16x8 Ar[4][2], Br[4][2];
  const int fr = lane & 15;
  const int kb = (lane >> 4) * 16;  // byte offset within 64-elem k (per ks add ks*64)

#define LOADA(buf, miB)                                                             \
  do {                                                                              \
    const ushort_t* sl = SLOT(buf, 0, wm);                                          \
    _Pragma("unroll") for (int mi = 0; mi < 4; mi++)                                \
        _Pragma("unroll") for (int ks = 0; ks < 2; ks++)                            \
            Ar[mi][ks] = read_frag(sl, (miB + mi) * 16 + fr, ks * 64 + kb);         \
  } while (0)
#define LOADB(buf, ns)                                                              \
  do {                                                                              \
    const ushort_t* sl = SLOT(buf, 1, wn >> 1);                                     \
    _Pragma("unroll") for (int nj = 0; nj < 2; nj++)                                \
        _Pragma("unroll") for (int ks = 0; ks < 2; ks++)                            \
            Br[(ns) * 2 + nj][ks] =                                                 \
                read_frag(sl, (wn & 1) * 64 + ((ns) * 2 + nj) * 16 + fr, ks * 64 + kb); \
  } while (0)
#define MFMA16(miB, ns)                                                             \
  do {                                                                              \
    _Pragma("unroll") for (int ks = 0; ks < 2; ks++)                                \
        _Pragma("unroll") for (int mi = 0; mi < 4; mi++)                            \
            _Pragma("unroll") for (int nj = 0; nj < 2; nj++)                        \
                acc[(miB) + mi][(ns) * 2 + nj] = __builtin_amdgcn_mfma_f32_16x16x32_bf16( \
                    Ar[mi][ks], Br[(ns) * 2 + nj][ks], acc[(miB) + mi][(ns) * 2 + nj], 0, 0, 0); \
  } while (0)

  const ushort_t* Ap1 = Ap + 128 * (long)lda;
  const ushort_t* Bp1 = Bp + 128 * (long)ldb;

  // Prologue: tile0 (A0,B0,A1,B1 -> buf0) + tile1.A0 -> buf1; drain tile0.
  STAGE(Ap, lda, 0, 0, 0, 0);
  STAGE(Bp, ldb, 0, 0, 1, 0);
  STAGE(Ap1, lda, 0, 0, 0, 1);
  STAGE(Bp1, ldb, 0, 0, 1, 1);
  STAGE(Ap, lda, 64, 1, 0, 0);
  WAIT_VM2();
  SBARRIER();

  const int NT2 = K >> 7;  // K/128, 2 K-tiles per iteration
  for (int it = 0; it < NT2; it++) {
    const int kt = it << 7;
    const int ktb = kt + 64;
    const int ktn = (kt + 128 < K) ? kt + 128 : K - 64;   // clamped re-stage: duplicate bytes, benign
    const int ktn2 = (kt + 192 < K) ? kt + 192 : K - 64;

    // P1: reads buf0 A[m0-3]+B[n0-1] (12 ds_read); stage (t+1).B0 -> buf1
    LOADA(0, 0); LOADB(0, 0);
    STAGE(Bp, ldb, ktb, 1, 1, 0);
    WAIT_LGKM8();
    SBARRIER();
    WAIT_LGKM0P();
    __builtin_amdgcn_s_setprio(1); MFMA16(0, 0); __builtin_amdgcn_s_setprio(0);
    // P2: reads buf0 B[n2-3]; stage (t+1).A1 -> buf1
    LOADB(0, 1);
    STAGE(Ap1, lda, ktb, 1, 0, 1);
    SBARRIER();
    WAIT_LGKM0P();
    __builtin_amdgcn_s_setprio(1); MFMA16(0, 1); __builtin_amdgcn_s_setprio(0);
    // P3: reads buf0 A[m4-7]; stage (t+1).B1 -> buf1
    LOADA(0, 4);
    STAGE(Bp1, ldb, ktb, 1, 1, 1);
    SBARRIER();
    WAIT_LGKM0P();
    __builtin_amdgcn_s_setprio(1); MFMA16(4, 0); __builtin_amdgcn_s_setprio(0);
    // P4 (merged): stage (t+2).A0 -> buf0; vmcnt(2) pre-barrier drains all of t+1;
    // single barrier; MFMA (reg-only) after.
    STAGE(Ap, lda, ktn, 0, 0, 0);
    WAIT_VM2();
    SBARRIER();
    __builtin_amdgcn_s_setprio(1); MFMA16(4, 1); __builtin_amdgcn_s_setprio(0);
    // P5: reads buf1 A[m0-3]+B[n0-1]; stage (t+2).B0 -> buf0
    LOADA(1, 0); LOADB(1, 0);
    STAGE(Bp, ldb, ktn, 0, 1, 0);
    WAIT_LGKM8();
    SBARRIER();
    WAIT_LGKM0P();
    __builtin_amdgcn_s_setprio(1); MFMA16(0, 0); __builtin_amdgcn_s_setprio(0);
    // P6: reads buf1 B[n2-3]; stage (t+2).A1 -> buf0
    LOADB(1, 1);
    STAGE(Ap1, lda, ktn, 0, 0, 1);
    SBARRIER();
    WAIT_LGKM0P();
    __builtin_amdgcn_s_setprio(1); MFMA16(0, 1); __builtin_amdgcn_s_setprio(0);
    // P7: reads buf1 A[m4-7]; stage (t+2).B1 -> buf0
    LOADA(1, 4);
    STAGE(Bp1, ldb, ktn, 0, 1, 1);
    SBARRIER();
    WAIT_LGKM0P();
    __builtin_amdgcn_s_setprio(1); MFMA16(4, 0); __builtin_amdgcn_s_setprio(0);
    // P8 (merged): stage (t+3).A0 -> buf1; vmcnt(2) pre-barrier drains all of t+2;
    // single barrier; MFMA after.
    STAGE(Ap, lda, ktn2, 1, 0, 0);
    WAIT_VM2();
    SBARRIER();
    __builtin_amdgcn_s_setprio(1); MFMA16(4, 1); __builtin_amdgcn_s_setprio(0);
  }

  // ---- Epilogue: drain in-flight stages, then per-wave LDS transpose -> 16B stores.
  WAIT_VM0();
  SBARRIER();
  {
    float* sl = reinterpret_cast<float*>(lds) + w * 2048;  // 8 KiB per wave; [16][68] f32
    const int rowQ = (lane >> 4) * 4;
    float bv[4];
#pragma unroll
    for (int ni = 0; ni < 4; ni++) bv[ni] = bias[(int)colBase + wn * 64 + ni * 16 + fr];
    const int rr = lane >> 2;        // 0..15: readback row
    const int cq = (lane & 3) * 16;  // 0..48: readback col quad
#pragma unroll
    for (int mi = 0; mi < 8; mi++) {
#pragma unroll
      for (int ni = 0; ni < 4; ni++) {
        const bool doRelu = ((int)colBase + wn * 64 + ni * 16 + fr) < relu_lim;
#pragma unroll
        for (int r = 0; r < 4; r++) {
          float v = acc[mi][ni][r] + bv[ni];
          if (doRelu) v = fmaxf(v, 0.f);
          sl[(rowQ + r) * 68 + ni * 16 + fr] = v;
        }
      }
      asm volatile("s_waitcnt lgkmcnt(0)" ::: "memory");
      __builtin_amdgcn_sched_barrier(0);
      float4 v0 = *reinterpret_cast<const float4*>(&sl[rr * 68 + cq]);
      float4 v1 = *reinterpret_cast<const float4*>(&sl[rr * 68 + cq + 4]);
      float4 v2 = *reinterpret_cast<const float4*>(&sl[rr * 68 + cq + 8]);
      float4 v3 = *reinterpret_cast<const float4*>(&sl[rr * 68 + cq + 12]);
      const long row = rowBase + wm * 128 + mi * 16 + rr;
      const long gc = colBase + wn * 64 + cq;
      if (OUT_F32) {
        float* dst = (float*)Cout + z * strideC + row * (long)ldc + gc;
        *reinterpret_cast<float4*>(dst) = v0;
        *reinterpret_cast<float4*>(dst + 4) = v1;
        *reinterpret_cast<float4*>(dst + 8) = v2;
        *reinterpret_cast<float4*>(dst + 12) = v3;
      } else {
        ushort_t* dst = (ushort_t*)Cout + z * strideC + row * (long)ldc + gc;
        us8 o0, o1;
        o0[0] = f2bf(v0.x); o0[1] = f2bf(v0.y); o0[2] = f2bf(v0.z); o0[3] = f2bf(v0.w);
        o0[4] = f2bf(v1.x); o0[5] = f2bf(v1.y); o0[6] = f2bf(v1.z); o0[7] = f2bf(v1.w);
        o1[0] = f2bf(v2.x); o1[1] = f2bf(v2.y); o1[2] = f2bf(v2.z); o1[3] = f2bf(v2.w);
        o1[4] = f2bf(v3.x); o1[5] = f2bf(v3.y); o1[6] = f2bf(v3.z); o1[7] = f2bf(v3.w);
        *reinterpret_cast<us8*>(dst) = o0;
        *reinterpret_cast<us8*>(dst + 8) = o1;
      }
      asm volatile("s_waitcnt lgkmcnt(0)" ::: "memory");  // reads retired before next mi overwrite
    }
  }
#undef SLOT
#undef STAGE
#undef LOADA
#undef LOADB
#undef MFMA16
}

// ---------------- KV state partials: [8][64][64][64], 4-wave blocks, LDS block-reduce --
__global__ __launch_bounds__(256) void k_kv_partial(const ushort_t* __restrict__ qkv,
                                                    float* __restrict__ partial) {
  const int bh = blockIdx.x;     // 0..63
  const int chunk = blockIdx.y;  // 0..7
  const int b = bh >> 4, h = bh & 15;
  const int t = threadIdx.x;
  const int w = t >> 6, lane = t & 63;
  const int d0 = (lane >> 2) * 4;
  const int e0 = (lane & 3) * 16;
  __shared__ float smem[16384];  // 64 KiB: per-wave staging (32K), then reduce (64K)
  float* kk = smem + w * 2048;         // [16][64]
  float* vv = smem + w * 2048 + 1024;  // [16][64]
  float acc[4][16];
#pragma unroll
  for (int di = 0; di < 4; di++)
#pragma unroll
    for (int j = 0; j < 16; j++) acc[di][j] = 0.f;

  const long rowbase = (long)b * 4096 + (long)chunk * 512 + (long)w * 128;
  for (int itr = 0; itr < 8; itr++) {
    __syncthreads();
#pragma unroll
    for (int rep = 0; rep < 4; rep++) {
      int lin = rep * 64 + lane;        // 0..255
      int op = lin >> 7;                // reps 0,1 -> k; reps 2,3 -> v
      int r = (lin >> 3) & 15;
      int c8 = (lin & 7) * 8;
      long m = rowbase + itr * 16 + r;
      us8 u = *reinterpret_cast<const us8*>(&qkv[m * 3072 + (op ? 2048 : 1024) + h * 64 + c8]);
      float* dst = (op ? vv : kk) + r * 64 + c8;
      float4 lo = {bf2f(u[0]), bf2f(u[1]), bf2f(u[2]), bf2f(u[3])};
      float4 hi = {bf2f(u[4]), bf2f(u[5]), bf2f(u[6]), bf2f(u[7])};
      *reinterpret_cast<float4*>(dst) = lo;
      *reinterpret_cast<float4*>(dst + 4) = hi;
    }
    __syncthreads();
#pragma unroll
    for (int ss = 0; ss < 16; ss++) {
      const float4 kq = *reinterpret_cast<const float4*>(&kk[ss * 64 + d0]);
#pragma unroll
      for (int jj = 0; jj < 4; jj++) {
        const float4 vq = *reinterpret_cast<const float4*>(&vv[ss * 64 + e0 + jj * 4]);
        acc[0][jj * 4 + 0] = fmaf(kq.x, vq.x, acc[0][jj * 4 + 0]);
        acc[0][jj * 4 + 1] = fmaf(kq.x, vq.y, acc[0][jj * 4 + 1]);
        acc[0][jj * 4 + 2] = fmaf(kq.x, vq.z, acc[0][jj * 4 + 2]);
        acc[0][jj * 4 + 3] = fmaf(kq.x, vq.w, acc[0][jj * 4 + 3]);
        acc[1][jj * 4 + 0] = fmaf(kq.y, vq.x, acc[1][jj * 4 + 0]);
        acc[1][jj * 4 + 1] = fmaf(kq.y, vq.y, acc[1][jj * 4 + 1]);
        acc[1][jj * 4 + 2] = fmaf(kq.y, vq.z, acc[1][jj * 4 + 2]);
        acc[1][jj * 4 + 3] = fmaf(kq.y, vq.w, acc[1][jj * 4 + 3]);
        acc[2][jj * 4 + 0] = fmaf(kq.z, vq.x, acc[2][jj * 4 + 0]);
        acc[2][jj * 4 + 1] = fmaf(kq.z, vq.y, acc[2][jj * 4 + 1]);
        acc[2][jj * 4 + 2] = fmaf(kq.z, vq.z, acc[2][jj * 4 + 2]);
        acc[2][jj * 4 + 3] = fmaf(kq.z, vq.w, acc[2][jj * 4 + 3]);
        acc[3][jj * 4 + 0] = fmaf(kq.w, vq.x, acc[3][jj * 4 + 0]);
        acc[3][jj * 4 + 1] = fmaf(kq.w, vq.y, acc[3][jj * 4 + 1]);
        acc[3][jj * 4 + 2] = fmaf(kq.w, vq.z, acc[3][jj * 4 + 2]);
        acc[3][jj * 4 + 3] = fmaf(kq.w, vq.w, acc[3][jj * 4 + 3]);
      }
    }
  }
  // block reduce: waves write acc to LDS, then each thread sums 16 outputs across waves
  __syncthreads();
#pragma unroll
  for (int di = 0; di < 4; di++)
#pragma unroll
    for (int j4 = 0; j4 < 4; j4++)
      *reinterpret_cast<float4*>(&smem[(w * 64 + lane) * 64 + di * 16 + j4 * 4]) =
          make_float4(acc[di][j4 * 4], acc[di][j4 * 4 + 1], acc[di][j4 * 4 + 2],
                      acc[di][j4 * 4 + 3]);
  __syncthreads();
  const int u = (t >> 4) * 4 + (t & 3);  // owner lane of (d,e) block
  const int di = (t >> 2) & 3;
  float4 r0 = {0, 0, 0, 0}, r1 = {0, 0, 0, 0}, r2 = {0, 0, 0, 0}, r3 = {0, 0, 0, 0};
#pragma unroll
  for (int ww = 0; ww < 4; ww++) {
    const float* base = &smem[(ww * 64 + u) * 64 + di * 16];
    float4 a0 = *reinterpret_cast<const float4*>(base);
    float4 a1 = *reinterpret_cast<const float4*>(base + 4);
    float4 a2 = *reinterpret_cast<const float4*>(base + 8);
    float4 a3 = *reinterpret_cast<const float4*>(base + 12);
    r0.x += a0.x; r0.y += a0.y; r0.z += a0.z; r0.w += a0.w;
    r1.x += a1.x; r1.y += a1.y; r1.z += a1.z; r1.w += a1.w;
    r2.x += a2.x; r2.y += a2.y; r2.z += a2.z; r2.w += a2.w;
    r3.x += a3.x; r3.y += a3.y; r3.z += a3.z; r3.w += a3.w;
  }
  float* dst = partial + ((long)chunk * 64 + bh) * 4096 + t * 16;
  *reinterpret_cast<float4*>(dst) = r0;
  *reinterpret_cast<float4*>(dst + 4) = r1;
  *reinterpret_cast<float4*>(dst + 8) = r2;
  *reinterpret_cast<float4*>(dst + 12) = r3;
}

__global__ __launch_bounds__(256) void k_kv_reduce(const float* __restrict__ partial,
                                                   float* __restrict__ kv) {
  int i4 = (blockIdx.x * 256 + threadIdx.x) * 4;
  float4 s = make_float4(0.f, 0.f, 0.f, 0.f);
#pragma unroll
  for (int c = 0; c < 8; c++) {
    float4 p = *reinterpret_cast<const float4*>(&partial[(long)c * 262144 + i4]);
    s.x += p.x; s.y += p.y; s.z += p.z; s.w += p.w;
  }
  *reinterpret_cast<float4*>(&kv[i4]) = s;
}

// ---------------- fused weight: FW_b[n][h*64+d] = sum_e kv[b,h][d][e] * ow[n][h*64+e]
__global__ __launch_bounds__(256) void k_fuse_w(const float* __restrict__ kv,
                                                const ushort_t* __restrict__ ow,
                                                ushort_t* __restrict__ qkv) {
  const int nt = blockIdx.x;
  const int h = blockIdx.y;
  const int b = blockIdx.z;
  const int t = threadIdx.x;
  const int nn = t >> 2;
  const int d0 = (t & 3) * 16;
  __shared__ float kvt[64][68];
  __shared__ ushort_t ows[64][68];
  const float* kvsrc = kv + (long)(b * 16 + h) * 4096;
  const int n0 = nt * 64;
#pragma unroll
  for (int rep = 0; rep < 16; rep++) {
    int lin = rep * 256 + t;
    int d = lin >> 6, e = lin & 63;
    kvt[e][d] = kvsrc[d * 64 + e];
  }
#pragma unroll
  for (int rep = 0; rep < 4; rep++) {
    int lin = rep * 256 + t;
    int r = lin >> 4, c4 = (lin & 15) * 4;
    *reinterpret_cast<ushort4*>(&ows[r][c4]) =
        *reinterpret_cast<const ushort4*>(&ow[(long)(n0 + r) * 1024 + h * 64 + c4]);
  }
  __syncthreads();
  float acc[16];
#pragma unroll
  for (int j = 0; j < 16; j++) acc[j] = 0.f;
  for (int e = 0; e < 64; e++) {
    float own = bf2f(ows[nn][e]);
#pragma unroll
    for (int jj = 0; jj < 4; jj++) {
      const float4 kq = *reinterpret_cast<const float4*>(&kvt[e][d0 + jj * 4]);
      acc[jj * 4 + 0] = fmaf(own, kq.x, acc[jj * 4 + 0]);
      acc[jj * 4 + 1] = fmaf(own, kq.y, acc[jj * 4 + 1]);
      acc[jj * 4 + 2] = fmaf(own, kq.z, acc[jj * 4 + 2]);
      acc[jj * 4 + 3] = fmaf(own, kq.w, acc[jj * 4 + 3]);
    }
  }
  ushort_t* dst = qkv + (long)(b * 1024 + n0 + nn) * 3072 + 1024 + h * 64 + d0;
#pragma unroll
  for (int jj = 0; jj < 4; jj++) {
    ushort4 o;
    o.x = f2bf(acc[jj * 4 + 0]); o.y = f2bf(acc[jj * 4 + 1]);
    o.z = f2bf(acc[jj * 4 + 2]); o.w = f2bf(acc[jj * 4 + 3]);
    *reinterpret_cast<ushort4*>(dst + jj * 4) = o;
  }
}

extern "C" void kernel_launch(void* const* d_in, const int* in_sizes, int n_in, void* d_out,
                              int out_size, void* d_ws, size_t ws_size, hipStream_t stream) {
  const float* x   = (const float*)d_in[0];
  const float* q_w = (const float*)d_in[1];
  const float* q_b = (const float*)d_in[2];
  const float* k_w = (const float*)d_in[3];
  const float* k_b = (const float*)d_in[4];
  const float* v_w = (const float*)d_in[5];
  const float* v_b = (const float*)d_in[6];
  const float* o_w = (const float*)d_in[7];
  const float* o_b = (const float*)d_in[8];
  float* out = (float*)d_out;

  char* ws = (char*)d_ws;
  ushort_t* xb    = (ushort_t*)(ws);              // 33,554,432  x as bf16
  ushort_t* wqkv  = (ushort_t*)(ws + 33554432);   //  6,291,456  [q_w;k_w;v_w] bf16
  ushort_t* owb   = (ushort_t*)(ws + 39845888);   //  2,097,152  o_w bf16 (wqkv+3*1M elems)
  float*    biasq = (float*)(ws + 41943040);      //     12,288  [q_b;k_b;v_b]
  ushort_t* qkv   = (ushort_t*)(ws + 41955328);   // 100,663,296 [M][3072] bf16
  float* partial = (float*)(ws);                  //  8,388,608  [8][64][4096] (recycles xb)
  float* kvbuf   = (float*)(ws + 33554432);       //  1,048,576  (recycles wqkv)

  // all packs in one launch: x (8192 blks) + weights (4096, dst wqkv..owb contiguous) + bias (12)
  k_pack_all<<<12300, 256, 0, stream>>>(x, q_w, k_w, v_w, o_w, q_b, k_b, v_b, xb, wqkv, biasq);

  // QKV projection: [16384 x 1024] x [3072 x 1024]^T (+bias, relu on cols<2048)
  k_gemm256<false><<<dim3(12, 64, 1), 512, 0, stream>>>(xb, 1024, 0, wqkv, 1024, 0,
                                                        biasq, 2048, qkv, 3072, 0, 1024);
  // KV state
  k_kv_partial<<<dim3(64, 8), 256, 0, stream>>>(qkv, partial);
  k_kv_reduce<<<256, 256, 0, stream>>>(partial, kvbuf);
  // fold KV into o_w (per-batch fused weight in dead k-columns of qkv rows 0..4095)
  k_fuse_w<<<dim3(16, 16, 4), 256, 0, stream>>>(kvbuf, owb, qkv);
  // out_b = relu(q)_b @ FW_b^T + o_b  — single batched launch (grid.z = 4)
  k_gemm256<true><<<dim3(4, 16, 4), 512, 0, stream>>>(
      qkv, 3072, (long)4096 * 3072, qkv + 1024, 3072, (long)1024 * 3072,
      o_b, 0, out, 1024, (long)4096 * 1024, 1024);
}